// Round 20
// baseline (1210.026 us; speedup 1.0000x reference)
//
#include <hip/hip_runtime.h>
#include <hip/hip_bf16.h>
#include <hip/hip_fp16.h>
#include <math.h>

#define N_NODES 10000
#define N_EDGES 320000
#define IN_SIZE 256
#define H1 8
#define D1 64
#define F1 512
#define H2 1
#define D2 64
#define F2 64
#define SLOT_STRIDE 128   // padded per-node edge bucket; P(deg>128) ~ e^-32
#define NBLOCKS 1024      // 4 blocks/CU x 256 CUs: guaranteed co-resident
#define NTHREADS (NBLOCKS * 256)

using f16x8 = __attribute__((ext_vector_type(8))) _Float16;
using f32x4 = __attribute__((ext_vector_type(4))) float;

#define PREP_X (N_NODES * IN_SIZE / 4)
#define PREP_W1 (IN_SIZE * F1)
#define PREP_W2 (F1 * F2)
#define GEMM1_TILES (8 * ((N_NODES + 63) / 64))   // 1256
#define GEMM2_TILES ((N_NODES + 63) / 64)         // 157

// ---- device-wide barrier (cross-XCD safe: device-scope atomics + fences) ----
__device__ __forceinline__ void grid_bar(int* bar, int target) {
  __syncthreads();
  if (threadIdx.x == 0) {
    __threadfence();                    // release: drain this block's stores
    atomicAdd(bar, 1);                  // device-scope arrive
    while (__hip_atomic_load(bar, __ATOMIC_ACQUIRE, __HIP_MEMORY_SCOPE_AGENT) < target) {
      __builtin_amdgcn_s_sleep(2);
    }
  }
  __syncthreads();
}

// ---- LDS-staged MFMA GEMM tile, chunked K (32 KB Bs reused per chunk) ----
template <int K>
__device__ __forceinline__ void gemm_tile(
    int rowBase, int colBase, const __half* __restrict__ A,
    const __half* __restrict__ BT, __half* __restrict__ Ch,
    const float* __restrict__ al, const float* __restrict__ ar,
    float* __restrict__ el, float* __restrict__ er,
    int M, int Ncols, int H, f16x8* Bs) {
  constexpr int KSTEPS = K / 32;
  constexpr int CH_STEPS = (KSTEPS > 8) ? 8 : KSTEPS;
  constexpr int NCHUNK = KSTEPS / CH_STEPS;
  constexpr int UPC = 4 * CH_STEPS;  // 16B units per column per chunk
  int tid = threadIdx.x;
  int w = tid >> 6, lane = tid & 63;
  int r16 = lane & 15, ko = lane >> 4;
  int rb = rowBase + w * 16;
  int arow = rb + r16;
  if (arow >= M) arow = M - 1;
  f32x4 acc[4] = {};
  for (int ch = 0; ch < NCHUNK; ++ch) {
    __syncthreads();  // protect Bs reuse (prev chunk/tile reads done)
    for (int u = tid; u < 64 * UPC; u += 256) {
      int col = u / UPC;
      int off = u % UPC;
      f16x8 v = *reinterpret_cast<const f16x8*>(
          BT + (size_t)(colBase + col) * K + ch * CH_STEPS * 32 + off * 8);
      Bs[u ^ (col & 7)] = v;
    }
    __syncthreads();
    const f16x8* Ap = reinterpret_cast<const f16x8*>(
        A + (size_t)arow * K + ch * CH_STEPS * 32 + ko * 8);
#pragma unroll
    for (int kk = 0; kk < CH_STEPS; ++kk) {
      f16x8 af = Ap[kk * 4];
#pragma unroll
      for (int c = 0; c < 4; ++c) {
        int col = c * 16 + r16;
        f16x8 bf = Bs[(col * UPC + kk * 4 + ko) ^ (col & 7)];
        acc[c] = __builtin_amdgcn_mfma_f32_16x16x32_f16(af, bf, acc[c], 0, 0, 0);
      }
    }
  }
  int h = colBase >> 6;
  float alv[4], arv[4];
#pragma unroll
  for (int c = 0; c < 4; ++c) {
    alv[c] = al[colBase + c * 16 + r16];
    arv[c] = ar[colBase + c * 16 + r16];
  }
#pragma unroll
  for (int r = 0; r < 4; ++r) {
    int row = rb + ko * 4 + r;
    bool ok = row < M;
    float pl = 0.f, pr = 0.f;
#pragma unroll
    for (int c = 0; c < 4; ++c) {
      float v = acc[c][r];
      if (ok) Ch[(size_t)row * Ncols + colBase + c * 16 + r16] = __float2half(v);
      pl += v * alv[c];
      pr += v * arv[c];
    }
#pragma unroll
    for (int o = 8; o > 0; o >>= 1) {
      pl += __shfl_xor(pl, o);
      pr += __shfl_xor(pr, o);
    }
    if (r16 == 0 && ok) {
      el[(size_t)row * H + h] = pl;
      er[(size_t)row * H + h] = pr;
    }
  }
}

__device__ __forceinline__ float leaky_exp(float v) {
  v = (v >= 0.f) ? v : 0.2f * v;
  return __expf(fminf(v, 80.f));
}

// ---- agg1 body (one node; block = node, wave = 128-ch tile) ----
__device__ __forceinline__ void agg1_node(
    int n, const int* __restrict__ cnt, const int* __restrict__ slots,
    const float* __restrict__ el, const float* __restrict__ er,
    const __half* __restrict__ fth, const float* __restrict__ bias,
    __half* __restrict__ out) {
  int t = threadIdx.x;
  int w = t >> 6, lane = t & 63;
  int e = lane >> 4;
  int sub = lane & 15;
  int chb = w * 128 + sub * 8;
  int h = chb >> 6;
  int beg = n * SLOT_STRIDE;
  int end = beg + min(cnt[n], SLOT_STRIDE);
  float er_h = er[n * 8 + h];
  float s_run = 0.f;
  float acc[8] = {0.f, 0.f, 0.f, 0.f, 0.f, 0.f, 0.f, 0.f};
  if (beg < end) {
    int iA = min(beg + e, end - 1);
    bool okA = (beg + e) < end;
    int sA = slots[iA];
    int iB = min(beg + 4 + e, end - 1);
    bool okB = (beg + 4 + e) < end;
    int sB = slots[iB];
    float elA = el[sA * 8 + h];
    uint4 ftA = *reinterpret_cast<const uint4*>(fth + (size_t)sA * F1 + chb);
    for (int c = beg; c < end; c += 4) {
      int iC = min(c + 8 + e, end - 1);
      bool okC = (c + 8 + e) < end;
      int sC = slots[iC];
      float elB = el[sB * 8 + h];
      uint4 ftB = *reinterpret_cast<const uint4*>(fth + (size_t)sB * F1 + chb);
      float ex = okA ? leaky_exp(elA + er_h) : 0.f;
      float2 f0 = __half22float2(*reinterpret_cast<const __half2*>(&ftA.x));
      float2 f1 = __half22float2(*reinterpret_cast<const __half2*>(&ftA.y));
      float2 f2 = __half22float2(*reinterpret_cast<const __half2*>(&ftA.z));
      float2 f3 = __half22float2(*reinterpret_cast<const __half2*>(&ftA.w));
      acc[0] += ex * f0.x; acc[1] += ex * f0.y;
      acc[2] += ex * f1.x; acc[3] += ex * f1.y;
      acc[4] += ex * f2.x; acc[5] += ex * f2.y;
      acc[6] += ex * f3.x; acc[7] += ex * f3.y;
      s_run += ex;
      sA = sB; okA = okB; elA = elB; ftA = ftB;
      sB = sC; okB = okC;
    }
  }
#pragma unroll
  for (int i = 0; i < 8; ++i) {
    acc[i] += __shfl_xor(acc[i], 16);
    acc[i] += __shfl_xor(acc[i], 32);
  }
  s_run += __shfl_xor(s_run, 16);
  s_run += __shfl_xor(s_run, 32);
  if (e == 0) {
    float inv = (s_run > 0.f) ? (1.f / s_run) : 0.f;
    uint4 pack;
    __half2* ph = reinterpret_cast<__half2*>(&pack);
#pragma unroll
    for (int i = 0; i < 4; ++i) {
      float v0 = acc[2 * i + 0] * inv + bias[chb + 2 * i + 0];
      float v1 = acc[2 * i + 1] * inv + bias[chb + 2 * i + 1];
      v0 = (v0 > 0.f) ? v0 : (__expf(v0) - 1.f);  // ELU
      v1 = (v1 > 0.f) ? v1 : (__expf(v1) - 1.f);
      ph[i] = __floats2half2_rn(v0, v1);
    }
    *reinterpret_cast<uint4*>(out + (size_t)n * F1 + chb) = pack;
  }
}

// ---- agg2 body (4 nodes per 256-thread unit; wave per node) ----
__device__ __forceinline__ void agg2_node(
    int u, const int* __restrict__ cnt, const int* __restrict__ slots,
    const float* __restrict__ el, const float* __restrict__ er,
    const __half* __restrict__ fth, const float* __restrict__ bias,
    float* __restrict__ out) {
  int t = threadIdx.x;
  int w = t >> 6, lane = t & 63;
  int n = u * 4 + w;
  int e = lane >> 3;
  int q = lane & 7;
  int chb = q * 8;
  int beg = n * SLOT_STRIDE;
  int end = beg + min(cnt[n], SLOT_STRIDE);
  float er_n = er[n];
  float s_run = 0.f;
  float acc[8] = {0.f, 0.f, 0.f, 0.f, 0.f, 0.f, 0.f, 0.f};
  if (beg < end) {
    int iA = min(beg + e, end - 1);
    bool okA = (beg + e) < end;
    int sA = slots[iA];
    int iB = min(beg + 8 + e, end - 1);
    bool okB = (beg + 8 + e) < end;
    int sB = slots[iB];
    float elA = el[sA];
    uint4 ftA = *reinterpret_cast<const uint4*>(fth + (size_t)sA * F2 + chb);
    for (int c = beg; c < end; c += 8) {
      int iC = min(c + 16 + e, end - 1);
      bool okC = (c + 16 + e) < end;
      int sC = slots[iC];
      float elB = el[sB];
      uint4 ftB = *reinterpret_cast<const uint4*>(fth + (size_t)sB * F2 + chb);
      float ex = okA ? leaky_exp(elA + er_n) : 0.f;
      float2 f0 = __half22float2(*reinterpret_cast<const __half2*>(&ftA.x));
      float2 f1 = __half22float2(*reinterpret_cast<const __half2*>(&ftA.y));
      float2 f2 = __half22float2(*reinterpret_cast<const __half2*>(&ftA.z));
      float2 f3 = __half22float2(*reinterpret_cast<const __half2*>(&ftA.w));
      acc[0] += ex * f0.x; acc[1] += ex * f0.y;
      acc[2] += ex * f1.x; acc[3] += ex * f1.y;
      acc[4] += ex * f2.x; acc[5] += ex * f2.y;
      acc[6] += ex * f3.x; acc[7] += ex * f3.y;
      s_run += ex;
      sA = sB; okA = okB; elA = elB; ftA = ftB;
      sB = sC; okB = okC;
    }
  }
#pragma unroll
  for (int i = 0; i < 8; ++i) {
    acc[i] += __shfl_xor(acc[i], 8);
    acc[i] += __shfl_xor(acc[i], 16);
    acc[i] += __shfl_xor(acc[i], 32);
  }
  s_run += __shfl_xor(s_run, 8);
  s_run += __shfl_xor(s_run, 16);
  s_run += __shfl_xor(s_run, 32);
  if (e == 0) {
    float inv = (s_run > 0.f) ? (1.f / s_run) : 0.f;
    float o[8];
#pragma unroll
    for (int i = 0; i < 8; ++i) o[i] = acc[i] * inv + bias[chb + i];
    float* op = &out[(size_t)n * F2 + chb];
    *reinterpret_cast<float4*>(op) = make_float4(o[0], o[1], o[2], o[3]);
    *reinterpret_cast<float4*>(op + 4) = make_float4(o[4], o[5], o[6], o[7]);
  }
}

// ---- persistent mega-kernel: 5 phases, 4 device-wide barriers ----
__global__ __launch_bounds__(256, 4) void mega_kernel(
    const float* __restrict__ x, const int* __restrict__ src,
    const int* __restrict__ dst,
    const float* __restrict__ W1, const float* __restrict__ al1,
    const float* __restrict__ ar1, const float* __restrict__ b1,
    const float* __restrict__ W2, const float* __restrict__ al2,
    const float* __restrict__ ar2, const float* __restrict__ b2,
    float* __restrict__ out,
    int* bar, int* cnt, int* slots,
    __half* xh, __half* W1T, __half* W2T,
    __half* ft1h, __half* h1h, __half* ft2h,
    float* el1, float* er1, float* el2, float* er2) {
  __shared__ f16x8 Bs[2048];  // 32 KB
  int tid = threadIdx.x;
  int gtid = blockIdx.x * 256 + tid;

  // ---- P0: conversions (xh, W1T, W2T) ----
  for (int i = gtid; i < PREP_X + PREP_W1 + PREP_W2; i += NTHREADS) {
    int j = i;
    if (j < PREP_X) {
      float4 v = reinterpret_cast<const float4*>(x)[j];
      reinterpret_cast<__half2*>(xh)[j * 2 + 0] = __floats2half2_rn(v.x, v.y);
      reinterpret_cast<__half2*>(xh)[j * 2 + 1] = __floats2half2_rn(v.z, v.w);
      continue;
    }
    j -= PREP_X;
    if (j < PREP_W1) {
      int k = j / F1, n = j % F1;
      W1T[(size_t)n * IN_SIZE + k] = __float2half(W1[j]);
      continue;
    }
    j -= PREP_W1;
    {
      int k = j / F2, n = j % F2;
      W2T[(size_t)n * F1 + k] = __float2half(W2[j]);
    }
  }
  grid_bar(bar, NBLOCKS * 1);

  // ---- P1: CSR-bucket scatter (by thread) + gemm1 tiles (by block) ----
  for (int e = gtid; e < N_EDGES; e += NTHREADS) {
    int d = dst[e];
    int p = atomicAdd(&cnt[d], 1);
    if (p < SLOT_STRIDE) slots[d * SLOT_STRIDE + p] = src[e];
  }
  for (int t2 = blockIdx.x; t2 < GEMM1_TILES; t2 += NBLOCKS) {
    gemm_tile<IN_SIZE>((t2 >> 3) * 64, (t2 & 7) * 64, xh, W1T, ft1h,
                       al1, ar1, el1, er1, N_NODES, F1, H1, Bs);
  }
  grid_bar(bar, NBLOCKS * 2);

  // ---- P2: agg1 ----
  for (int n = blockIdx.x; n < N_NODES; n += NBLOCKS)
    agg1_node(n, cnt, slots, el1, er1, ft1h, b1, h1h);
  grid_bar(bar, NBLOCKS * 3);

  // ---- P3: gemm2 (K=512, two-chunk staging) ----
  for (int t2 = blockIdx.x; t2 < GEMM2_TILES; t2 += NBLOCKS) {
    gemm_tile<F1>(t2 * 64, 0, h1h, W2T, ft2h,
                  al2, ar2, el2, er2, N_NODES, F2, H2, Bs);
  }
  grid_bar(bar, NBLOCKS * 4);

  // ---- P4: agg2 ----
  for (int u = blockIdx.x; u < N_NODES / 4; u += NBLOCKS)
    agg2_node(u, cnt, slots, el2, er2, ft2h, b2, out);
}

extern "C" void kernel_launch(void* const* d_in, const int* in_sizes, int n_in,
                              void* d_out, int out_size, void* d_ws, size_t ws_size,
                              hipStream_t stream) {
  const float* x   = (const float*)d_in[0];
  const int*   src = (const int*)d_in[1];
  const int*   dst = (const int*)d_in[2];
  const float* W1  = (const float*)d_in[3];
  const float* al1 = (const float*)d_in[4];
  const float* ar1 = (const float*)d_in[5];
  const float* b1  = (const float*)d_in[6];
  const float* W2  = (const float*)d_in[7];
  const float* al2 = (const float*)d_in[8];
  const float* ar2 = (const float*)d_in[9];
  const float* b2  = (const float*)d_in[10];
  float* out = (float*)d_out;

  char* ws = (char*)d_ws;
  size_t off = 0;
  auto alloc = [&](size_t bytes) -> void* {
    void* p = ws + off;
    off += (bytes + 255) & ~(size_t)255;
    return p;
  };
  size_t zbeg = off;
  int* bar = (int*)alloc(256);
  int* cnt = (int*)alloc((size_t)N_NODES * 4);
  size_t zend = off;
  int* slots = (int*)alloc((size_t)N_NODES * SLOT_STRIDE * 4);
  __half* xh   = (__half*)alloc((size_t)N_NODES * IN_SIZE * 2);
  __half* W1T  = (__half*)alloc((size_t)IN_SIZE * F1 * 2);
  __half* W2T  = (__half*)alloc((size_t)F1 * F2 * 2);
  __half* ft1h = (__half*)alloc((size_t)N_NODES * F1 * 2);
  __half* h1h  = (__half*)alloc((size_t)N_NODES * F1 * 2);
  __half* ft2h = (__half*)alloc((size_t)N_NODES * F2 * 2);
  float* el1 = (float*)alloc((size_t)N_NODES * H1 * 4);
  float* er1 = (float*)alloc((size_t)N_NODES * H1 * 4);
  float* el2 = (float*)alloc((size_t)N_NODES * 4);
  float* er2 = (float*)alloc((size_t)N_NODES * 4);
  (void)ws_size; (void)in_sizes; (void)n_in; (void)out_size;

  hipMemsetAsync(ws + zbeg, 0, zend - zbeg, stream);

  mega_kernel<<<NBLOCKS, 256, 0, stream>>>(
      x, src, dst, W1, al1, ar1, b1, W2, al2, ar2, b2, out,
      bar, cnt, slots, xh, W1T, W2T, ft1h, h1h, ft2h,
      el1, er1, el2, er2);
}

// Round 21
// 108.692 us; speedup vs baseline: 11.1326x; 11.1326x over previous
//
#include <hip/hip_runtime.h>
#include <hip/hip_bf16.h>
#include <hip/hip_fp16.h>
#include <math.h>

#define N_NODES 10000
#define N_EDGES 320000
#define IN_SIZE 256
#define H1 8
#define D1 64
#define F1 512
#define H2 1
#define D2 64
#define F2 64
#define SLOT_STRIDE 128   // padded per-node edge bucket; P(deg>128) ~ e^-32

using f16x8 = __attribute__((ext_vector_type(8))) _Float16;
using f32x4 = __attribute__((ext_vector_type(4))) float;

// ---- fused prep: x->f16, W1^T->f16, W2^T->f16, AND direct CSR-bucket scatter ----
#define PREP_X (N_NODES * IN_SIZE / 4)
#define PREP_W1 (IN_SIZE * F1)
#define PREP_W2 (F1 * F2)
__global__ void prep_kernel(const float* __restrict__ x, __half* __restrict__ xh,
                            const float* __restrict__ W1, __half* __restrict__ W1T,
                            const float* __restrict__ W2, __half* __restrict__ W2T,
                            const int* __restrict__ src, const int* __restrict__ dst,
                            int* __restrict__ cnt, int* __restrict__ slots) {
  int i = blockIdx.x * blockDim.x + threadIdx.x;
  if (i < PREP_X) {
    float4 v = reinterpret_cast<const float4*>(x)[i];
    reinterpret_cast<__half2*>(xh)[i * 2 + 0] = __floats2half2_rn(v.x, v.y);
    reinterpret_cast<__half2*>(xh)[i * 2 + 1] = __floats2half2_rn(v.z, v.w);
    return;
  }
  i -= PREP_X;
  if (i < PREP_W1) {
    int k = i / F1, n = i % F1;
    W1T[(size_t)n * IN_SIZE + k] = __float2half(W1[i]);
    return;
  }
  i -= PREP_W1;
  if (i < PREP_W2) {
    int k = i / F2, n = i % F2;
    W2T[(size_t)n * F1 + k] = __float2half(W2[i]);
    return;
  }
  i -= PREP_W2;
  if (i < N_EDGES) {
    int d = dst[i];
    int p = atomicAdd(&cnt[d], 1);
    if (p < SLOT_STRIDE) slots[d * SLOT_STRIDE + p] = src[i];
  }
}

// ---- shared LDS-staged MFMA GEMM tile (64 rows x 64 cols per block) ----
template <int KSTEPS>
__device__ __forceinline__ void gemm_tile(
    int rowBase, int colBase, const __half* __restrict__ A,
    const __half* __restrict__ BT, __half* __restrict__ Ch,
    const float* __restrict__ al, const float* __restrict__ ar,
    float* __restrict__ el, float* __restrict__ er,
    int M, int Ncols, int H, f16x8* Bs) {
  constexpr int K = KSTEPS * 32;
  constexpr int UPC = 4 * KSTEPS;  // 16B units per column
  int tid = threadIdx.x;
  for (int u = tid; u < 64 * UPC; u += 256) {
    int col = u / UPC;
    int off = u % UPC;
    f16x8 v = *reinterpret_cast<const f16x8*>(BT + (size_t)(colBase + col) * K + off * 8);
    Bs[u ^ (col & 7)] = v;
  }
  __syncthreads();
  int w = tid >> 6, lane = tid & 63;
  int r16 = lane & 15, ko = lane >> 4;
  int rb = rowBase + w * 16;
  int arow = rb + r16;
  if (arow >= M) arow = M - 1;
  const f16x8* Ap = reinterpret_cast<const f16x8*>(A + (size_t)arow * K + ko * 8);
  f32x4 acc[4] = {};
#pragma unroll
  for (int kk = 0; kk < KSTEPS; ++kk) {
    f16x8 af = Ap[kk * 4];
#pragma unroll
    for (int c = 0; c < 4; ++c) {
      int col = c * 16 + r16;
      f16x8 bf = Bs[(col * UPC + kk * 4 + ko) ^ (col & 7)];
      acc[c] = __builtin_amdgcn_mfma_f32_16x16x32_f16(af, bf, acc[c], 0, 0, 0);
    }
  }
  int h = colBase >> 6;
  float alv[4], arv[4];
#pragma unroll
  for (int c = 0; c < 4; ++c) {
    alv[c] = al[colBase + c * 16 + r16];
    arv[c] = ar[colBase + c * 16 + r16];
  }
#pragma unroll
  for (int r = 0; r < 4; ++r) {
    int row = rb + (lane >> 4) * 4 + r;
    bool ok = row < M;
    float pl = 0.f, pr = 0.f;
#pragma unroll
    for (int c = 0; c < 4; ++c) {
      float v = acc[c][r];
      if (ok) Ch[(size_t)row * Ncols + colBase + c * 16 + r16] = __float2half(v);
      pl += v * alv[c];
      pr += v * arv[c];
    }
#pragma unroll
    for (int o = 8; o > 0; o >>= 1) {
      pl += __shfl_xor(pl, o);
      pr += __shfl_xor(pr, o);
    }
    if (r16 == 0 && ok) {
      el[(size_t)row * H + h] = pl;
      er[(size_t)row * H + h] = pr;
    }
  }
}

template <int KSTEPS>
__global__ __launch_bounds__(256) void gemm_lds(
    const __half* __restrict__ A, const __half* __restrict__ BT,
    __half* __restrict__ Ch, const float* __restrict__ al,
    const float* __restrict__ ar, float* __restrict__ el,
    float* __restrict__ er, int M, int Ncols, int H) {
  __shared__ f16x8 Bs[64 * 4 * KSTEPS];
  gemm_tile<KSTEPS>(blockIdx.y * 64, blockIdx.x * 64,
                    A, BT, Ch, al, ar, el, er, M, Ncols, H, Bs);
}

__device__ __forceinline__ float leaky_exp(float v) {
  v = (v >= 0.f) ? v : 0.2f * v;
  return __expf(fminf(v, 80.f));
}

// ---- aggregation layer 1 (exp fused): block = node, wave = 128-ch tile ----
__global__ __launch_bounds__(256) void agg1_kernel(
    const int* __restrict__ cnt, const int* __restrict__ slots,
    const float* __restrict__ el, const float* __restrict__ er,
    const __half* __restrict__ fth, const float* __restrict__ bias,
    __half* __restrict__ out) {
  int t = threadIdx.x;
  int w = t >> 6, lane = t & 63;
  int n = blockIdx.x;
  int e = lane >> 4;
  int sub = lane & 15;
  int chb = w * 128 + sub * 8;
  int h = chb >> 6;
  int beg = n * SLOT_STRIDE;
  int end = beg + min(cnt[n], SLOT_STRIDE);
  float er_h = er[n * 8 + h];
  float s_run = 0.f;
  float acc[8] = {0.f, 0.f, 0.f, 0.f, 0.f, 0.f, 0.f, 0.f};
  if (beg < end) {
    int iA = min(beg + e, end - 1);
    bool okA = (beg + e) < end;
    int sA = slots[iA];
    int iB = min(beg + 4 + e, end - 1);
    bool okB = (beg + 4 + e) < end;
    int sB = slots[iB];
    float elA = el[sA * 8 + h];
    uint4 ftA = *reinterpret_cast<const uint4*>(fth + (size_t)sA * F1 + chb);
    for (int c = beg; c < end; c += 4) {
      int iC = min(c + 8 + e, end - 1);
      bool okC = (c + 8 + e) < end;
      int sC = slots[iC];
      float elB = el[sB * 8 + h];
      uint4 ftB = *reinterpret_cast<const uint4*>(fth + (size_t)sB * F1 + chb);
      float ex = okA ? leaky_exp(elA + er_h) : 0.f;
      float2 f0 = __half22float2(*reinterpret_cast<const __half2*>(&ftA.x));
      float2 f1 = __half22float2(*reinterpret_cast<const __half2*>(&ftA.y));
      float2 f2 = __half22float2(*reinterpret_cast<const __half2*>(&ftA.z));
      float2 f3 = __half22float2(*reinterpret_cast<const __half2*>(&ftA.w));
      acc[0] += ex * f0.x; acc[1] += ex * f0.y;
      acc[2] += ex * f1.x; acc[3] += ex * f1.y;
      acc[4] += ex * f2.x; acc[5] += ex * f2.y;
      acc[6] += ex * f3.x; acc[7] += ex * f3.y;
      s_run += ex;
      sA = sB; okA = okB; elA = elB; ftA = ftB;
      sB = sC; okB = okC;
    }
  }
#pragma unroll
  for (int i = 0; i < 8; ++i) {
    acc[i] += __shfl_xor(acc[i], 16);
    acc[i] += __shfl_xor(acc[i], 32);
  }
  s_run += __shfl_xor(s_run, 16);
  s_run += __shfl_xor(s_run, 32);
  if (e == 0) {
    float inv = (s_run > 0.f) ? (1.f / s_run) : 0.f;
    uint4 pack;
    __half2* ph = reinterpret_cast<__half2*>(&pack);
#pragma unroll
    for (int i = 0; i < 4; ++i) {
      float v0 = acc[2 * i + 0] * inv + bias[chb + 2 * i + 0];
      float v1 = acc[2 * i + 1] * inv + bias[chb + 2 * i + 1];
      v0 = (v0 > 0.f) ? v0 : (__expf(v0) - 1.f);  // ELU
      v1 = (v1 > 0.f) ? v1 : (__expf(v1) - 1.f);
      ph[i] = __floats2half2_rn(v0, v1);
    }
    *reinterpret_cast<uint4*>(out + (size_t)n * F1 + chb) = pack;
  }
}

// ---- aggregation layer 2 (H=1, exp fused): wave per node ----
template <int NPB>
__global__ __launch_bounds__(NPB * 64) void agg2_kernel(
    const int* __restrict__ cnt, const int* __restrict__ slots,
    const float* __restrict__ el, const float* __restrict__ er,
    const __half* __restrict__ fth, const float* __restrict__ bias,
    float* __restrict__ out) {
  int t = threadIdx.x;
  int w = t >> 6, lane = t & 63;
  int n = blockIdx.x * NPB + w;
  int e = lane >> 3;
  int q = lane & 7;
  int chb = q * 8;
  int beg = n * SLOT_STRIDE;
  int end = beg + min(cnt[n], SLOT_STRIDE);
  float er_n = er[n];
  float s_run = 0.f;
  float acc[8] = {0.f, 0.f, 0.f, 0.f, 0.f, 0.f, 0.f, 0.f};
  if (beg < end) {
    int iA = min(beg + e, end - 1);
    bool okA = (beg + e) < end;
    int sA = slots[iA];
    int iB = min(beg + 8 + e, end - 1);
    bool okB = (beg + 8 + e) < end;
    int sB = slots[iB];
    float elA = el[sA];
    uint4 ftA = *reinterpret_cast<const uint4*>(fth + (size_t)sA * F2 + chb);
    for (int c = beg; c < end; c += 8) {
      int iC = min(c + 16 + e, end - 1);
      bool okC = (c + 16 + e) < end;
      int sC = slots[iC];
      float elB = el[sB];
      uint4 ftB = *reinterpret_cast<const uint4*>(fth + (size_t)sB * F2 + chb);
      float ex = okA ? leaky_exp(elA + er_n) : 0.f;
      float2 f0 = __half22float2(*reinterpret_cast<const __half2*>(&ftA.x));
      float2 f1 = __half22float2(*reinterpret_cast<const __half2*>(&ftA.y));
      float2 f2 = __half22float2(*reinterpret_cast<const __half2*>(&ftA.z));
      float2 f3 = __half22float2(*reinterpret_cast<const __half2*>(&ftA.w));
      acc[0] += ex * f0.x; acc[1] += ex * f0.y;
      acc[2] += ex * f1.x; acc[3] += ex * f1.y;
      acc[4] += ex * f2.x; acc[5] += ex * f2.y;
      acc[6] += ex * f3.x; acc[7] += ex * f3.y;
      s_run += ex;
      sA = sB; okA = okB; elA = elB; ftA = ftB;
      sB = sC; okB = okC;
    }
  }
#pragma unroll
  for (int i = 0; i < 8; ++i) {
    acc[i] += __shfl_xor(acc[i], 8);
    acc[i] += __shfl_xor(acc[i], 16);
    acc[i] += __shfl_xor(acc[i], 32);
  }
  s_run += __shfl_xor(s_run, 8);
  s_run += __shfl_xor(s_run, 16);
  s_run += __shfl_xor(s_run, 32);
  if (e == 0) {
    float inv = (s_run > 0.f) ? (1.f / s_run) : 0.f;
    float o[8];
#pragma unroll
    for (int i = 0; i < 8; ++i) o[i] = acc[i] * inv + bias[chb + i];
    float* op = &out[(size_t)n * F2 + chb];
    *reinterpret_cast<float4*>(op) = make_float4(o[0], o[1], o[2], o[3]);
    *reinterpret_cast<float4*>(op + 4) = make_float4(o[4], o[5], o[6], o[7]);
  }
}

extern "C" void kernel_launch(void* const* d_in, const int* in_sizes, int n_in,
                              void* d_out, int out_size, void* d_ws, size_t ws_size,
                              hipStream_t stream) {
  const float* x   = (const float*)d_in[0];
  const int*   src = (const int*)d_in[1];
  const int*   dst = (const int*)d_in[2];
  const float* W1  = (const float*)d_in[3];
  const float* al1 = (const float*)d_in[4];
  const float* ar1 = (const float*)d_in[5];
  const float* b1  = (const float*)d_in[6];
  const float* W2  = (const float*)d_in[7];
  const float* al2 = (const float*)d_in[8];
  const float* ar2 = (const float*)d_in[9];
  const float* b2  = (const float*)d_in[10];
  float* out = (float*)d_out;

  char* ws = (char*)d_ws;
  size_t off = 0;
  auto alloc = [&](size_t bytes) -> void* {
    void* p = ws + off;
    off += (bytes + 255) & ~(size_t)255;
    return p;
  };
  size_t zbeg = off;
  int* cnt = (int*)alloc((size_t)N_NODES * 4);
  size_t zend = off;
  int* slots = (int*)alloc((size_t)N_NODES * SLOT_STRIDE * 4);
  __half* xh   = (__half*)alloc((size_t)N_NODES * IN_SIZE * 2);
  __half* W1T  = (__half*)alloc((size_t)IN_SIZE * F1 * 2);
  __half* W2T  = (__half*)alloc((size_t)F1 * F2 * 2);
  __half* ft1h = (__half*)alloc((size_t)N_NODES * F1 * 2);
  __half* h1h  = (__half*)alloc((size_t)N_NODES * F1 * 2);
  __half* ft2h = (__half*)alloc((size_t)N_NODES * F2 * 2);
  float* el1 = (float*)alloc((size_t)N_NODES * H1 * 4);
  float* er1 = (float*)alloc((size_t)N_NODES * H1 * 4);
  float* el2 = (float*)alloc((size_t)N_NODES * 4);
  float* er2 = (float*)alloc((size_t)N_NODES * 4);
  (void)ws_size; (void)in_sizes; (void)n_in; (void)out_size;

  hipMemsetAsync(ws + zbeg, 0, zend - zbeg, stream);

  dim3 b256(256);
  int prep_total = PREP_X + PREP_W1 + PREP_W2 + N_EDGES;

  // 1 dispatch: conversions + direct padded-bucket CSR scatter
  prep_kernel<<<(prep_total + 255) / 256, b256, 0, stream>>>(
      x, xh, W1, W1T, W2, W2T, src, dst, cnt, slots);

  // ---- layer 1 ----
  gemm_lds<IN_SIZE / 32><<<dim3(F1 / 64, (N_NODES + 63) / 64), b256, 0, stream>>>(
      xh, W1T, ft1h, al1, ar1, el1, er1, N_NODES, F1, H1);
  agg1_kernel<<<N_NODES, b256, 0, stream>>>(
      cnt, slots, el1, er1, ft1h, b1, h1h);

  // ---- layer 2 ----
  gemm_lds<F1 / 32><<<dim3(F2 / 64, (N_NODES + 63) / 64), b256, 0, stream>>>(
      h1h, W2T, ft2h, al2, ar2, el2, er2, N_NODES, F2, H2);
  agg2_kernel<4><<<N_NODES / 4, b256, 0, stream>>>(
      cnt, slots, el2, er2, ft2h, b2, out);
}

// Round 22
// 106.539 us; speedup vs baseline: 11.3576x; 1.0202x over previous
//
#include <hip/hip_runtime.h>
#include <hip/hip_bf16.h>
#include <hip/hip_fp16.h>
#include <math.h>

#define N_NODES 10000
#define N_EDGES 320000
#define IN_SIZE 256
#define H1 8
#define D1 64
#define F1 512
#define H2 1
#define D2 64
#define F2 64
#define SLOT_STRIDE 128   // padded per-node edge bucket; P(deg>128) ~ e^-32

using f16x8 = __attribute__((ext_vector_type(8))) _Float16;
using f32x4 = __attribute__((ext_vector_type(4))) float;

// ---- fused prep: x->f16, W1^T->f16, W2^T->f16, AND direct CSR-bucket scatter ----
#define PREP_X (N_NODES * IN_SIZE / 4)
#define PREP_W1 (IN_SIZE * F1)
#define PREP_W2 (F1 * F2)
__global__ void prep_kernel(const float* __restrict__ x, __half* __restrict__ xh,
                            const float* __restrict__ W1, __half* __restrict__ W1T,
                            const float* __restrict__ W2, __half* __restrict__ W2T,
                            const int* __restrict__ src, const int* __restrict__ dst,
                            int* __restrict__ cnt, int* __restrict__ slots) {
  int i = blockIdx.x * blockDim.x + threadIdx.x;
  if (i < PREP_X) {
    float4 v = reinterpret_cast<const float4*>(x)[i];
    reinterpret_cast<__half2*>(xh)[i * 2 + 0] = __floats2half2_rn(v.x, v.y);
    reinterpret_cast<__half2*>(xh)[i * 2 + 1] = __floats2half2_rn(v.z, v.w);
    return;
  }
  i -= PREP_X;
  if (i < PREP_W1) {
    int k = i / F1, n = i % F1;
    W1T[(size_t)n * IN_SIZE + k] = __float2half(W1[i]);
    return;
  }
  i -= PREP_W1;
  if (i < PREP_W2) {
    int k = i / F2, n = i % F2;
    W2T[(size_t)n * F1 + k] = __float2half(W2[i]);
    return;
  }
  i -= PREP_W2;
  if (i < N_EDGES) {
    int d = dst[i];
    int p = atomicAdd(&cnt[d], 1);
    if (p < SLOT_STRIDE) slots[d * SLOT_STRIDE + p] = src[i];
  }
}

// ---- shared LDS-staged MFMA GEMM tile (64 rows x 64 cols per block) ----
template <int KSTEPS>
__device__ __forceinline__ void gemm_tile(
    int rowBase, int colBase, const __half* __restrict__ A,
    const __half* __restrict__ BT, __half* __restrict__ Ch,
    const float* __restrict__ al, const float* __restrict__ ar,
    float* __restrict__ el, float* __restrict__ er,
    int M, int Ncols, int H, f16x8* Bs) {
  constexpr int K = KSTEPS * 32;
  constexpr int UPC = 4 * KSTEPS;  // 16B units per column
  int tid = threadIdx.x;
  for (int u = tid; u < 64 * UPC; u += 256) {
    int col = u / UPC;
    int off = u % UPC;
    f16x8 v = *reinterpret_cast<const f16x8*>(BT + (size_t)(colBase + col) * K + off * 8);
    Bs[u ^ (col & 7)] = v;
  }
  __syncthreads();
  int w = tid >> 6, lane = tid & 63;
  int r16 = lane & 15, ko = lane >> 4;
  int rb = rowBase + w * 16;
  int arow = rb + r16;
  if (arow >= M) arow = M - 1;
  const f16x8* Ap = reinterpret_cast<const f16x8*>(A + (size_t)arow * K + ko * 8);
  f32x4 acc[4] = {};
#pragma unroll
  for (int kk = 0; kk < KSTEPS; ++kk) {
    f16x8 af = Ap[kk * 4];
#pragma unroll
    for (int c = 0; c < 4; ++c) {
      int col = c * 16 + r16;
      f16x8 bf = Bs[(col * UPC + kk * 4 + ko) ^ (col & 7)];
      acc[c] = __builtin_amdgcn_mfma_f32_16x16x32_f16(af, bf, acc[c], 0, 0, 0);
    }
  }
  int h = colBase >> 6;
  float alv[4], arv[4];
#pragma unroll
  for (int c = 0; c < 4; ++c) {
    alv[c] = al[colBase + c * 16 + r16];
    arv[c] = ar[colBase + c * 16 + r16];
  }
#pragma unroll
  for (int r = 0; r < 4; ++r) {
    int row = rb + (lane >> 4) * 4 + r;
    bool ok = row < M;
    float pl = 0.f, pr = 0.f;
#pragma unroll
    for (int c = 0; c < 4; ++c) {
      float v = acc[c][r];
      if (ok) Ch[(size_t)row * Ncols + colBase + c * 16 + r16] = __float2half(v);
      pl += v * alv[c];
      pr += v * arv[c];
    }
#pragma unroll
    for (int o = 8; o > 0; o >>= 1) {
      pl += __shfl_xor(pl, o);
      pr += __shfl_xor(pr, o);
    }
    if (r16 == 0 && ok) {
      el[(size_t)row * H + h] = pl;
      er[(size_t)row * H + h] = pr;
    }
  }
}

template <int KSTEPS>
__global__ __launch_bounds__(256) void gemm_lds(
    const __half* __restrict__ A, const __half* __restrict__ BT,
    __half* __restrict__ Ch, const float* __restrict__ al,
    const float* __restrict__ ar, float* __restrict__ el,
    float* __restrict__ er, int M, int Ncols, int H) {
  __shared__ f16x8 Bs[64 * 4 * KSTEPS];
  gemm_tile<KSTEPS>(blockIdx.y * 64, blockIdx.x * 64,
                    A, BT, Ch, al, ar, el, er, M, Ncols, H, Bs);
}

__device__ __forceinline__ float leaky_exp(float v) {
  v = (v >= 0.f) ? v : 0.2f * v;
  return __expf(fminf(v, 80.f));
}

__device__ __forceinline__ void fma8(float* acc, float ex, const uint4& ft) {
  float2 f0 = __half22float2(*reinterpret_cast<const __half2*>(&ft.x));
  float2 f1 = __half22float2(*reinterpret_cast<const __half2*>(&ft.y));
  float2 f2 = __half22float2(*reinterpret_cast<const __half2*>(&ft.z));
  float2 f3 = __half22float2(*reinterpret_cast<const __half2*>(&ft.w));
  acc[0] += ex * f0.x; acc[1] += ex * f0.y;
  acc[2] += ex * f1.x; acc[3] += ex * f1.y;
  acc[4] += ex * f2.x; acc[5] += ex * f2.y;
  acc[6] += ex * f3.x; acc[7] += ex * f3.y;
}

// ---- aggregation layer 1 (exp fused): block = node, wave = 128-ch tile ----
// Each lane owns TWO edge sub-slots per iteration ({c+e, c+4+e}, 8 edges/iter):
// 4 ft + 2 el + 2 slot loads in flight, half the iterations of the 4-edge
// version. 3-stage schedule: slots 2 iters ahead, el/ft 1 iter ahead.
__global__ __launch_bounds__(256) void agg1_kernel(
    const int* __restrict__ cnt, const int* __restrict__ slots,
    const float* __restrict__ el, const float* __restrict__ er,
    const __half* __restrict__ fth, const float* __restrict__ bias,
    __half* __restrict__ out) {
  int t = threadIdx.x;
  int w = t >> 6, lane = t & 63;
  int n = blockIdx.x;
  int e = lane >> 4;
  int sub = lane & 15;
  int chb = w * 128 + sub * 8;
  int h = chb >> 6;
  int beg = n * SLOT_STRIDE;
  int end = beg + min(cnt[n], SLOT_STRIDE);
  float er_h = er[n * 8 + h];
  float s_run = 0.f;
  float acc[8] = {0.f, 0.f, 0.f, 0.f, 0.f, 0.f, 0.f, 0.f};
  if (beg < end) {
    // stage A (compute this iter), stage B (slots for next iter)
    int i0 = min(beg + e, end - 1), i1 = min(beg + 4 + e, end - 1);
    bool ok0A = (beg + e) < end, ok1A = (beg + 4 + e) < end;
    int s0A = slots[i0], s1A = slots[i1];
    int j0 = min(beg + 8 + e, end - 1), j1 = min(beg + 12 + e, end - 1);
    bool ok0B = (beg + 8 + e) < end, ok1B = (beg + 12 + e) < end;
    int s0B = slots[j0], s1B = slots[j1];
    float el0A = el[s0A * 8 + h], el1A = el[s1A * 8 + h];
    uint4 ft0A = *reinterpret_cast<const uint4*>(fth + (size_t)s0A * F1 + chb);
    uint4 ft1A = *reinterpret_cast<const uint4*>(fth + (size_t)s1A * F1 + chb);
    for (int c = beg; c < end; c += 8) {
      // prefetch slots 2 iterations ahead
      int c2 = c + 16;
      int k0 = min(c2 + e, end - 1), k1 = min(c2 + 4 + e, end - 1);
      bool ok0C = (c2 + e) < end, ok1C = (c2 + 4 + e) < end;
      int s0C = slots[k0], s1C = slots[k1];
      // prefetch el/ft 1 iteration ahead (from stage-B slots)
      float el0B = el[s0B * 8 + h], el1B = el[s1B * 8 + h];
      uint4 ft0B = *reinterpret_cast<const uint4*>(fth + (size_t)s0B * F1 + chb);
      uint4 ft1B = *reinterpret_cast<const uint4*>(fth + (size_t)s1B * F1 + chb);
      // compute current pair
      float ex0 = ok0A ? leaky_exp(el0A + er_h) : 0.f;
      float ex1 = ok1A ? leaky_exp(el1A + er_h) : 0.f;
      fma8(acc, ex0, ft0A);
      fma8(acc, ex1, ft1A);
      s_run += ex0 + ex1;
      // shift pipeline
      ok0A = ok0B; ok1A = ok1B;
      el0A = el0B; el1A = el1B;
      ft0A = ft0B; ft1A = ft1B;
      s0B = s0C; s1B = s1C;
      ok0B = ok0C; ok1B = ok1C;
    }
  }
  // reduce over 4 edge slots (xor 16, 32)
#pragma unroll
  for (int i = 0; i < 8; ++i) {
    acc[i] += __shfl_xor(acc[i], 16);
    acc[i] += __shfl_xor(acc[i], 32);
  }
  s_run += __shfl_xor(s_run, 16);
  s_run += __shfl_xor(s_run, 32);
  if (e == 0) {
    float inv = (s_run > 0.f) ? (1.f / s_run) : 0.f;
    uint4 pack;
    __half2* ph = reinterpret_cast<__half2*>(&pack);
#pragma unroll
    for (int i = 0; i < 4; ++i) {
      float v0 = acc[2 * i + 0] * inv + bias[chb + 2 * i + 0];
      float v1 = acc[2 * i + 1] * inv + bias[chb + 2 * i + 1];
      v0 = (v0 > 0.f) ? v0 : (__expf(v0) - 1.f);  // ELU
      v1 = (v1 > 0.f) ? v1 : (__expf(v1) - 1.f);
      ph[i] = __floats2half2_rn(v0, v1);
    }
    *reinterpret_cast<uint4*>(out + (size_t)n * F1 + chb) = pack;
  }
}

// ---- aggregation layer 2 (H=1, exp fused): wave per node ----
// Each lane owns TWO edge sub-slots ({c+e, c+8+e}, 16 edges/iter).
template <int NPB>
__global__ __launch_bounds__(NPB * 64) void agg2_kernel(
    const int* __restrict__ cnt, const int* __restrict__ slots,
    const float* __restrict__ el, const float* __restrict__ er,
    const __half* __restrict__ fth, const float* __restrict__ bias,
    float* __restrict__ out) {
  int t = threadIdx.x;
  int w = t >> 6, lane = t & 63;
  int n = blockIdx.x * NPB + w;
  int e = lane >> 3;
  int q = lane & 7;
  int chb = q * 8;
  int beg = n * SLOT_STRIDE;
  int end = beg + min(cnt[n], SLOT_STRIDE);
  float er_n = er[n];
  float s_run = 0.f;
  float acc[8] = {0.f, 0.f, 0.f, 0.f, 0.f, 0.f, 0.f, 0.f};
  if (beg < end) {
    int i0 = min(beg + e, end - 1), i1 = min(beg + 8 + e, end - 1);
    bool ok0A = (beg + e) < end, ok1A = (beg + 8 + e) < end;
    int s0A = slots[i0], s1A = slots[i1];
    int j0 = min(beg + 16 + e, end - 1), j1 = min(beg + 24 + e, end - 1);
    bool ok0B = (beg + 16 + e) < end, ok1B = (beg + 24 + e) < end;
    int s0B = slots[j0], s1B = slots[j1];
    float el0A = el[s0A], el1A = el[s1A];
    uint4 ft0A = *reinterpret_cast<const uint4*>(fth + (size_t)s0A * F2 + chb);
    uint4 ft1A = *reinterpret_cast<const uint4*>(fth + (size_t)s1A * F2 + chb);
    for (int c = beg; c < end; c += 16) {
      int c2 = c + 32;
      int k0 = min(c2 + e, end - 1), k1 = min(c2 + 8 + e, end - 1);
      bool ok0C = (c2 + e) < end, ok1C = (c2 + 8 + e) < end;
      int s0C = slots[k0], s1C = slots[k1];
      float el0B = el[s0B], el1B = el[s1B];
      uint4 ft0B = *reinterpret_cast<const uint4*>(fth + (size_t)s0B * F2 + chb);
      uint4 ft1B = *reinterpret_cast<const uint4*>(fth + (size_t)s1B * F2 + chb);
      float ex0 = ok0A ? leaky_exp(el0A + er_n) : 0.f;
      float ex1 = ok1A ? leaky_exp(el1A + er_n) : 0.f;
      fma8(acc, ex0, ft0A);
      fma8(acc, ex1, ft1A);
      s_run += ex0 + ex1;
      ok0A = ok0B; ok1A = ok1B;
      el0A = el0B; el1A = el1B;
      ft0A = ft0B; ft1A = ft1B;
      s0B = s0C; s1B = s1C;
      ok0B = ok0C; ok1B = ok1C;
    }
  }
  // reduce over 8 edge slots (xor 8, 16, 32)
#pragma unroll
  for (int i = 0; i < 8; ++i) {
    acc[i] += __shfl_xor(acc[i], 8);
    acc[i] += __shfl_xor(acc[i], 16);
    acc[i] += __shfl_xor(acc[i], 32);
  }
  s_run += __shfl_xor(s_run, 8);
  s_run += __shfl_xor(s_run, 16);
  s_run += __shfl_xor(s_run, 32);
  if (e == 0) {
    float inv = (s_run > 0.f) ? (1.f / s_run) : 0.f;
    float o[8];
#pragma unroll
    for (int i = 0; i < 8; ++i) o[i] = acc[i] * inv + bias[chb + i];
    float* op = &out[(size_t)n * F2 + chb];
    *reinterpret_cast<float4*>(op) = make_float4(o[0], o[1], o[2], o[3]);
    *reinterpret_cast<float4*>(op + 4) = make_float4(o[4], o[5], o[6], o[7]);
  }
}

extern "C" void kernel_launch(void* const* d_in, const int* in_sizes, int n_in,
                              void* d_out, int out_size, void* d_ws, size_t ws_size,
                              hipStream_t stream) {
  const float* x   = (const float*)d_in[0];
  const int*   src = (const int*)d_in[1];
  const int*   dst = (const int*)d_in[2];
  const float* W1  = (const float*)d_in[3];
  const float* al1 = (const float*)d_in[4];
  const float* ar1 = (const float*)d_in[5];
  const float* b1  = (const float*)d_in[6];
  const float* W2  = (const float*)d_in[7];
  const float* al2 = (const float*)d_in[8];
  const float* ar2 = (const float*)d_in[9];
  const float* b2  = (const float*)d_in[10];
  float* out = (float*)d_out;

  char* ws = (char*)d_ws;
  size_t off = 0;
  auto alloc = [&](size_t bytes) -> void* {
    void* p = ws + off;
    off += (bytes + 255) & ~(size_t)255;
    return p;
  };
  size_t zbeg = off;
  int* cnt = (int*)alloc((size_t)N_NODES * 4);
  size_t zend = off;
  int* slots = (int*)alloc((size_t)N_NODES * SLOT_STRIDE * 4);
  __half* xh   = (__half*)alloc((size_t)N_NODES * IN_SIZE * 2);
  __half* W1T  = (__half*)alloc((size_t)IN_SIZE * F1 * 2);
  __half* W2T  = (__half*)alloc((size_t)F1 * F2 * 2);
  __half* ft1h = (__half*)alloc((size_t)N_NODES * F1 * 2);
  __half* h1h  = (__half*)alloc((size_t)N_NODES * F1 * 2);
  __half* ft2h = (__half*)alloc((size_t)N_NODES * F2 * 2);
  float* el1 = (float*)alloc((size_t)N_NODES * H1 * 4);
  float* er1 = (float*)alloc((size_t)N_NODES * H1 * 4);
  float* el2 = (float*)alloc((size_t)N_NODES * 4);
  float* er2 = (float*)alloc((size_t)N_NODES * 4);
  (void)ws_size; (void)in_sizes; (void)n_in; (void)out_size;

  hipMemsetAsync(ws + zbeg, 0, zend - zbeg, stream);

  dim3 b256(256);
  int prep_total = PREP_X + PREP_W1 + PREP_W2 + N_EDGES;

  // 1 dispatch: conversions + direct padded-bucket CSR scatter
  prep_kernel<<<(prep_total + 255) / 256, b256, 0, stream>>>(
      x, xh, W1, W1T, W2, W2T, src, dst, cnt, slots);

  // ---- layer 1 ----
  gemm_lds<IN_SIZE / 32><<<dim3(F1 / 64, (N_NODES + 63) / 64), b256, 0, stream>>>(
      xh, W1T, ft1h, al1, ar1, el1, er1, N_NODES, F1, H1);
  agg1_kernel<<<N_NODES, b256, 0, stream>>>(
      cnt, slots, el1, er1, ft1h, b1, h1h);

  // ---- layer 2 ----
  gemm_lds<F1 / 32><<<dim3(F2 / 64, (N_NODES + 63) / 64), b256, 0, stream>>>(
      h1h, W2T, ft2h, al2, ar2, el2, er2, N_NODES, F2, H2);
  agg2_kernel<4><<<N_NODES / 4, b256, 0, stream>>>(
      cnt, slots, el2, er2, ft2h, b2, out);
}